// Round 1
// baseline (649.094 us; speedup 1.0000x reference)
//
#include <hip/hip_runtime.h>
#include <math.h>

static constexpr int M_ROWS   = 200000;
static constexpr int NUM_NODE = 150;
static constexpr int ROW_F    = NUM_NODE * 4;        // 600 floats per row
static constexpr int BLOCKS   = 2048;                // 8 blocks/CU worth of work
static constexpr int WPB      = 4;                   // waves per block (256 threads)
static constexpr int TOTAL_WAVES = BLOCKS * WPB;     // 8192 persistent waves

__global__ __launch_bounds__(256, 6) void obstacle_to_lane_kernel(
    const float* __restrict__ lf,       // (M, 150, 4) f32
    const float* __restrict__ obs_pos,  // (N, 2) f32
    const int*   __restrict__ mask,     // (M, 1) i32
    float*       __restrict__ out)      // [M*2 proj | M*2 idx | M*2 rep]
{
    const int wave = threadIdx.x >> 6;
    const int lane = threadIdx.x & 63;
    const int wid  = blockIdx.x * WPB + wave;

    // balanced contiguous chunk per wave: 24 or 25 rows
    const int base = M_ROWS / TOTAL_WAVES;            // 24
    const int rem  = M_ROWS % TOTAL_WAVES;            // 3392
    const int m0   = wid * base + (wid < rem ? wid : rem);
    const int m1   = m0 + base + (wid < rem ? 1 : 0);

    // per-lane node indices covering the FULL row (nodes 0..149)
    const int  j0   = lane;                                    // 0..63
    const int  j1   = lane + 64;                               // 64..127
    const int  j2c  = (lane + 128 <= NUM_NODE - 1) ? (lane + 128) : (NUM_NODE - 1); // clamp to 149
    const bool amin0 = (j0 >= 1);                              // argmin domain is [1,148]
    const bool amin2 = (lane + 128 <= NUM_NODE - 2);           // lanes 0..20

    const float* row = lf + (size_t)m0 * ROW_F;

    // prime the pipeline: row m0 + its obstacle
    float4 c0 = *reinterpret_cast<const float4*>(row + 4 * j0);
    float4 c1 = *reinterpret_cast<const float4*>(row + 4 * j1);
    float4 c2 = *reinterpret_cast<const float4*>(row + 4 * j2c);
    int obs0 = mask[m0];
    float rx = obs_pos[2 * obs0];
    float ry = obs_pos[2 * obs0 + 1];

    for (int m = m0; m < m1; ++m) {
        // ---- issue next row's loads first (stay ~6 VMEM in flight) ----
        float4 n0, n1, n2;
        float nrx, nry;
        const bool has_next = (m + 1 < m1);
        if (has_next) {
            const float* nrow = row + ROW_F;
            n0 = *reinterpret_cast<const float4*>(nrow + 4 * j0);
            n1 = *reinterpret_cast<const float4*>(nrow + 4 * j1);
            n2 = *reinterpret_cast<const float4*>(nrow + 4 * j2c);
            const int nobs = mask[m + 1];
            nrx = obs_pos[2 * nobs];
            nry = obs_pos[2 * nobs + 1];
        }

        // ---- argmin over nodes 1..148 of (x-rx)^2 + (y-ry)^2 ----
        float best_d = INFINITY;
        int   best_j = 1 << 30;
        {
            float dx = __fsub_rn(c0.x, rx), dy = __fsub_rn(c0.y, ry);
            float d  = __fadd_rn(__fmul_rn(dx, dx), __fmul_rn(dy, dy));
            if (amin0 && d < best_d) { best_d = d; best_j = j0; }
            dx = __fsub_rn(c1.x, rx); dy = __fsub_rn(c1.y, ry);
            d  = __fadd_rn(__fmul_rn(dx, dx), __fmul_rn(dy, dy));
            if (d < best_d) { best_d = d; best_j = j1; }
            dx = __fsub_rn(c2.x, rx); dy = __fsub_rn(c2.y, ry);
            d  = __fadd_rn(__fmul_rn(dx, dx), __fmul_rn(dy, dy));
            if (amin2 && d < best_d) { best_d = d; best_j = lane + 128; }
        }
        // wave-wide argmin reduction; ties -> smaller index (jnp.argmin semantics)
        #pragma unroll
        for (int off = 32; off > 0; off >>= 1) {
            const float od = __shfl_down(best_d, off, 64);
            const int   oj = __shfl_down(best_j, off, 64);
            if (od < best_d || (od == best_d && oj < best_j)) { best_d = od; best_j = oj; }
        }
        const int min_idx = __shfl(best_j, 0, 64);

        // ---- neighbor nodes via register shuffles (row is fully resident in regs) ----
        // node q lives on lane (q & 63), register group (q >> 6)
        auto pick = [&](int q) -> float4 {
            const int sl = q & 63;
            const int rr = q >> 6;                       // wave-uniform
            const float4 s = (rr == 0) ? c0 : ((rr == 1) ? c1 : c2);
            float4 r;
            r.x = __shfl(s.x, sl, 64);
            r.y = __shfl(s.y, sl, 64);
            r.z = __shfl(s.z, sl, 64);
            r.w = __shfl(s.w, sl, 64);
            return r;
        };
        const float4 na = pick(min_idx - 1);   // node_prev
        const float4 nc = pick(min_idx);       // min_node
        const float4 nb = pick(min_idx + 1);   // node_next

        // dist_prev / dist_next over all 4 features, numpy left-to-right order, no FMA contraction
        float t, s;
        t = __fsub_rn(na.x, nc.x); s = __fmul_rn(t, t);
        t = __fsub_rn(na.y, nc.y); s = __fadd_rn(s, __fmul_rn(t, t));
        t = __fsub_rn(na.z, nc.z); s = __fadd_rn(s, __fmul_rn(t, t));
        t = __fsub_rn(na.w, nc.w); s = __fadd_rn(s, __fmul_rn(t, t));
        const float dist_prev = s;
        t = __fsub_rn(nb.x, nc.x); s = __fmul_rn(t, t);
        t = __fsub_rn(nb.y, nc.y); s = __fadd_rn(s, __fmul_rn(t, t));
        t = __fsub_rn(nb.z, nc.z); s = __fadd_rn(s, __fmul_rn(t, t));
        t = __fsub_rn(nb.w, nc.w); s = __fadd_rn(s, __fmul_rn(t, t));
        const float dist_next = s;

        float sx, sy, ex, ey;
        int ib;
        if (dist_next < dist_prev) {            // before=min_idx, after=min_idx+1
            ib = min_idx;     sx = nc.x; sy = nc.y; ex = nb.x; ey = nb.y;
        } else {                                // before=min_idx-1, after=min_idx
            ib = min_idx - 1; sx = na.x; sy = na.y; ex = nc.x; ey = nc.y;
        }

        const float lvx = __fsub_rn(ex, sx);
        const float lvy = __fsub_rn(ey, sy);
        const float mag = __fsqrt_rn(__fadd_rn(__fmul_rn(lvx, lvx), __fmul_rn(lvy, lvy)));
        const float ux  = __fdiv_rn(lvx, mag);
        const float uy  = __fdiv_rn(lvy, mag);
        const float pm  = __fadd_rn(__fmul_rn(__fsub_rn(rx, sx), ux),
                                    __fmul_rn(__fsub_rn(ry, sy), uy));
        const float px  = __fadd_rn(sx, __fmul_rn(pm, ux));
        const float py  = __fadd_rn(sy, __fmul_rn(pm, uy));

        // one 3-lane float2 store covers proj / idx / rep
        if (lane < 3) {
            float2 v;
            size_t off;
            if (lane == 0) {
                v = make_float2(px, py);
                off = 2 * (size_t)m;
            } else if (lane == 1) {
                v = make_float2((float)ib, (float)(ib + 1));
                off = 2 * (size_t)M_ROWS + 2 * (size_t)m;
            } else {
                v = make_float2(rx, ry);
                off = 4 * (size_t)M_ROWS + 2 * (size_t)m;
            }
            *reinterpret_cast<float2*>(out + off) = v;
        }

        // rotate pipeline registers
        if (has_next) {
            row += ROW_F;
            c0 = n0; c1 = n1; c2 = n2;
            rx = nrx; ry = nry;
        }
    }
}

extern "C" void kernel_launch(void* const* d_in, const int* in_sizes, int n_in,
                              void* d_out, int out_size, void* d_ws, size_t ws_size,
                              hipStream_t stream) {
    const float* lf      = (const float*)d_in[0];
    const float* obs_pos = (const float*)d_in[1];
    const int*   mask    = (const int*)d_in[2];
    float*       out     = (float*)d_out;

    hipLaunchKernelGGL(obstacle_to_lane_kernel, dim3(BLOCKS), dim3(256), 0, stream,
                       lf, obs_pos, mask, out);
}

// Round 2
// 611.652 us; speedup vs baseline: 1.0612x; 1.0612x over previous
//
#include <hip/hip_runtime.h>
#include <math.h>

static constexpr int M_ROWS   = 200000;
static constexpr int NUM_NODE = 150;
static constexpr int ROW_F    = NUM_NODE * 4;        // 600 floats per row
static constexpr int ROWS_PER_BLOCK = 8;             // 4 waves x 2 rows each
// grid = 200000 / 8 = 25000 blocks -> dense sliding window across the tensor

__global__ __launch_bounds__(256) void obstacle_to_lane_kernel(
    const float* __restrict__ lf,       // (M, 150, 4) f32
    const float* __restrict__ obs_pos,  // (N, 2) f32
    const int*   __restrict__ mask,     // (M, 1) i32
    float*       __restrict__ out)      // [M*2 proj | M*2 idx | M*2 rep]
{
    const int wave = threadIdx.x >> 6;
    const int lane = threadIdx.x & 63;
    const int mA = blockIdx.x * ROWS_PER_BLOCK + wave * 2;   // 25000*8 == 200000 exactly
    const int mB = mA + 1;

    // per-lane node indices covering the FULL row (nodes 0..149)
    const int  j0 = lane;                                     // 0..63
    const int  j1 = lane + 64;                                // 64..127
    const int  j2c = (lane + 128 < NUM_NODE) ? (lane + 128) : (NUM_NODE - 1);
    const bool amin0 = (j0 >= 1);                             // argmin domain [1,148]
    const bool amin2 = (lane + 128 <= NUM_NODE - 2);          // lanes 0..20

    const float* rowA = lf + (size_t)mA * ROW_F;
    const float* rowB = rowA + ROW_F;

    // ---- issue ALL loads up front: 6 row loads + both mask->obs chains ----
    const int oA = mask[mA];
    const int oB = mask[mB];
    const float4 a0 = *reinterpret_cast<const float4*>(rowA + 4 * j0);
    const float4 a1 = *reinterpret_cast<const float4*>(rowA + 4 * j1);
    const float4 a2 = *reinterpret_cast<const float4*>(rowA + 4 * j2c);
    const float4 b0 = *reinterpret_cast<const float4*>(rowB + 4 * j0);
    const float4 b1 = *reinterpret_cast<const float4*>(rowB + 4 * j1);
    const float4 b2 = *reinterpret_cast<const float4*>(rowB + 4 * j2c);
    const float rxA = obs_pos[2 * oA], ryA = obs_pos[2 * oA + 1];
    const float rxB = obs_pos[2 * oB], ryB = obs_pos[2 * oB + 1];

    // ---- argmin over nodes 1..148 of (x-rx)^2 + (y-ry)^2, both rows ----
    float dA = INFINITY; int jA = 1 << 30;
    float dB = INFINITY; int jB = 1 << 30;
    {
        float dx, dy, d;
        dx = __fsub_rn(a0.x, rxA); dy = __fsub_rn(a0.y, ryA);
        d  = __fadd_rn(__fmul_rn(dx, dx), __fmul_rn(dy, dy));
        if (amin0 && d < dA) { dA = d; jA = j0; }
        dx = __fsub_rn(b0.x, rxB); dy = __fsub_rn(b0.y, ryB);
        d  = __fadd_rn(__fmul_rn(dx, dx), __fmul_rn(dy, dy));
        if (amin0 && d < dB) { dB = d; jB = j0; }

        dx = __fsub_rn(a1.x, rxA); dy = __fsub_rn(a1.y, ryA);
        d  = __fadd_rn(__fmul_rn(dx, dx), __fmul_rn(dy, dy));
        if (d < dA) { dA = d; jA = j1; }
        dx = __fsub_rn(b1.x, rxB); dy = __fsub_rn(b1.y, ryB);
        d  = __fadd_rn(__fmul_rn(dx, dx), __fmul_rn(dy, dy));
        if (d < dB) { dB = d; jB = j1; }

        dx = __fsub_rn(a2.x, rxA); dy = __fsub_rn(a2.y, ryA);
        d  = __fadd_rn(__fmul_rn(dx, dx), __fmul_rn(dy, dy));
        if (amin2 && d < dA) { dA = d; jA = lane + 128; }
        dx = __fsub_rn(b2.x, rxB); dy = __fsub_rn(b2.y, ryB);
        d  = __fadd_rn(__fmul_rn(dx, dx), __fmul_rn(dy, dy));
        if (amin2 && d < dB) { dB = d; jB = lane + 128; }
    }

    // ---- fused wave-wide argmin reduction (both rows' bpermute chains interleave) ----
    #pragma unroll
    for (int off = 32; off > 0; off >>= 1) {
        const float odA = __shfl_down(dA, off, 64);
        const int   ojA = __shfl_down(jA, off, 64);
        const float odB = __shfl_down(dB, off, 64);
        const int   ojB = __shfl_down(jB, off, 64);
        if (odA < dA || (odA == dA && ojA < jA)) { dA = odA; jA = ojA; }
        if (odB < dB || (odB == dB && ojB < jB)) { dB = odB; jB = ojB; }
    }
    const int min_idxA = __shfl(jA, 0, 64);
    const int min_idxB = __shfl(jB, 0, 64);

    // ---- neighbor nodes via register shuffles (rows fully resident in regs) ----
    auto pick = [&](const float4& s0, const float4& s1, const float4& s2, int q) -> float4 {
        const int sl = q & 63;
        const int rr = q >> 6;                       // wave-uniform
        const float4 s = (rr == 0) ? s0 : ((rr == 1) ? s1 : s2);
        float4 r;
        r.x = __shfl(s.x, sl, 64);
        r.y = __shfl(s.y, sl, 64);
        r.z = __shfl(s.z, sl, 64);
        r.w = __shfl(s.w, sl, 64);
        return r;
    };

    // epilogue math, exact numpy op order, no FMA contraction
    auto epilogue = [&](const float4& na, const float4& nc, const float4& nb,
                        int min_idx, float rx, float ry,
                        float& px, float& py, int& ib) {
        float t, s;
        t = __fsub_rn(na.x, nc.x); s = __fmul_rn(t, t);
        t = __fsub_rn(na.y, nc.y); s = __fadd_rn(s, __fmul_rn(t, t));
        t = __fsub_rn(na.z, nc.z); s = __fadd_rn(s, __fmul_rn(t, t));
        t = __fsub_rn(na.w, nc.w); s = __fadd_rn(s, __fmul_rn(t, t));
        const float dist_prev = s;
        t = __fsub_rn(nb.x, nc.x); s = __fmul_rn(t, t);
        t = __fsub_rn(nb.y, nc.y); s = __fadd_rn(s, __fmul_rn(t, t));
        t = __fsub_rn(nb.z, nc.z); s = __fadd_rn(s, __fmul_rn(t, t));
        t = __fsub_rn(nb.w, nc.w); s = __fadd_rn(s, __fmul_rn(t, t));
        const float dist_next = s;

        float sx, sy, ex, ey;
        if (dist_next < dist_prev) {            // before=min_idx, after=min_idx+1
            ib = min_idx;     sx = nc.x; sy = nc.y; ex = nb.x; ey = nb.y;
        } else {                                // before=min_idx-1, after=min_idx
            ib = min_idx - 1; sx = na.x; sy = na.y; ex = nc.x; ey = nc.y;
        }

        const float lvx = __fsub_rn(ex, sx);
        const float lvy = __fsub_rn(ey, sy);
        const float mag = __fsqrt_rn(__fadd_rn(__fmul_rn(lvx, lvx), __fmul_rn(lvy, lvy)));
        const float ux  = __fdiv_rn(lvx, mag);
        const float uy  = __fdiv_rn(lvy, mag);
        const float pm  = __fadd_rn(__fmul_rn(__fsub_rn(rx, sx), ux),
                                    __fmul_rn(__fsub_rn(ry, sy), uy));
        px = __fadd_rn(sx, __fmul_rn(pm, ux));
        py = __fadd_rn(sy, __fmul_rn(pm, uy));
    };

    const float4 naA = pick(a0, a1, a2, min_idxA - 1);
    const float4 ncA = pick(a0, a1, a2, min_idxA);
    const float4 nbA = pick(a0, a1, a2, min_idxA + 1);
    const float4 naB = pick(b0, b1, b2, min_idxB - 1);
    const float4 ncB = pick(b0, b1, b2, min_idxB);
    const float4 nbB = pick(b0, b1, b2, min_idxB + 1);

    float pxA, pyA, pxB, pyB;
    int ibA, ibB;
    epilogue(naA, ncA, nbA, min_idxA, rxA, ryA, pxA, pyA, ibA);
    epilogue(naB, ncB, nbB, min_idxB, rxB, ryB, pxB, pyB, ibB);

    // ---- 6-lane store: lanes 0-2 row A, lanes 3-5 row B ----
    if (lane < 6) {
        const bool isB  = lane >= 3;
        const int  m    = isB ? mB : mA;
        const int  slot = isB ? lane - 3 : lane;
        float2 v; size_t off;
        if (slot == 0) {
            v = make_float2(isB ? pxB : pxA, isB ? pyB : pyA);
            off = 2 * (size_t)m;
        } else if (slot == 1) {
            const int ib = isB ? ibB : ibA;
            v = make_float2((float)ib, (float)(ib + 1));
            off = 2 * (size_t)M_ROWS + 2 * (size_t)m;
        } else {
            v = make_float2(isB ? rxB : rxA, isB ? ryB : ryA);
            off = 4 * (size_t)M_ROWS + 2 * (size_t)m;
        }
        *reinterpret_cast<float2*>(out + off) = v;
    }
}

extern "C" void kernel_launch(void* const* d_in, const int* in_sizes, int n_in,
                              void* d_out, int out_size, void* d_ws, size_t ws_size,
                              hipStream_t stream) {
    const float* lf      = (const float*)d_in[0];
    const float* obs_pos = (const float*)d_in[1];
    const int*   mask    = (const int*)d_in[2];
    float*       out     = (float*)d_out;

    const int grid = M_ROWS / ROWS_PER_BLOCK;   // 25000
    hipLaunchKernelGGL(obstacle_to_lane_kernel, dim3(grid), dim3(256), 0, stream,
                       lf, obs_pos, mask, out);
}